// Round 15
// baseline (290.367 us; speedup 1.0000x reference)
//
#include <hip/hip_runtime.h>

typedef __attribute__((ext_vector_type(8))) __bf16 bf16x8;
typedef __attribute__((ext_vector_type(4))) float float4_;
typedef __attribute__((ext_vector_type(4))) unsigned short ushort4_;
typedef __attribute__((ext_vector_type(8))) unsigned short ushort8_;

// Weights stored as packed MFMA A-fragment tiles of 512 bf16, order [kt][ntile].
// Activations in LDS as B-fragment tiles, order [kt][mtile] (4 m-tiles = 64 pts).
// elem (n|pt, k) within tile: ((k>>3)&3)*128 + (n&15)*8 + (k&7)
// -> every wave fragment access is base + lane*16B: coalesced / 2-way-free banks.
#define OFF_W0T 0        // Kp=64  (KT=2),  NTB=16
#define OFF_W1T 16384    // Kp=256 x4,      NTB=16
#define OFF_W2T 81920
#define OFF_W3T 147456
#define OFF_W4T 212992
#define OFF_W5T 278528   // Kp=320 (KT=10), NTB=16
#define OFF_W6T 360448
#define OFF_W7T 425984   // W7[:,1:257]
#define OFF_WCT 491520   // N=128 -> NTB=8, Kp=256
#define BF16_TOTAL 524288
#define WSF_BYTE_OFF (BF16_TOTAL * 2)  // f32: w7sig[256], b7a[256]

__device__ __forceinline__ unsigned short f2b(float v) {
  union { float f; unsigned u; } a; a.f = v;
  unsigned r = a.u + 0x7fffu + ((a.u >> 16) & 1u);
  return (unsigned short)(r >> 16);
}

__device__ __forceinline__ bf16x8 bzero() {
  union { ushort8_ u; bf16x8 b; } z;
  ushort8_ t = {0, 0, 0, 0, 0, 0, 0, 0};
  z.u = t;
  return z.b;
}

// 4x f32 -> 4x bf16 (RNE) via gfx950 packed cvt when available.
__device__ __forceinline__ ushort4_ pack4(float4_ v) {
#if __has_builtin(__builtin_amdgcn_cvt_pk_bf16_f32)
  auto p0 = __builtin_amdgcn_cvt_pk_bf16_f32(v.x, v.y);
  auto p1 = __builtin_amdgcn_cvt_pk_bf16_f32(v.z, v.w);
  union { decltype(p0) p; unsigned u; } u0, u1;
  u0.p = p0; u1.p = p1;
  ushort4_ r;
  r.x = (unsigned short)(u0.u & 0xffffu); r.y = (unsigned short)(u0.u >> 16);
  r.z = (unsigned short)(u1.u & 0xffffu); r.w = (unsigned short)(u1.u >> 16);
  return r;
#else
  ushort4_ r; r.x = f2b(v.x); r.y = f2b(v.y); r.z = f2b(v.z); r.w = f2b(v.w);
  return r;
#endif
}

// ---------------- weight prep: coalesced reads, MFMA-tile packed ----------
__global__ __launch_bounds__(256) void prep_kernel(
    const float* __restrict__ W0, const float* __restrict__ W1,
    const float* __restrict__ W2, const float* __restrict__ W3,
    const float* __restrict__ W4, const float* __restrict__ W5,
    const float* __restrict__ W6, const float* __restrict__ W7,
    const float* __restrict__ Wc, const float* __restrict__ b7,
    unsigned short* __restrict__ wsb, float* __restrict__ wsf)
{
  int i = blockIdx.x * 256 + threadIdx.x;
  const float* src; int rs, K, n, k2, nt16; unsigned short* base;
  if (i < 8192)        { int t = i;          n = t & 255; k2 = t >> 8; src = W0; rs = 256; K = 39;  nt16 = 16; base = wsb + OFF_W0T; }
  else if (i < 139264) { int t = i - 8192;   int l = t >> 15; t &= 32767;
                         n = t & 255; k2 = t >> 8;
                         src = (l == 0) ? W1 : (l == 1) ? W2 : (l == 2) ? W3 : W4;
                         rs = 256; K = 256; nt16 = 16; base = wsb + OFF_W1T + l * 65536; }
  else if (i < 180224) { int t = i - 139264; n = t & 255; k2 = t >> 8; src = W5;     rs = 256; K = 295; nt16 = 16; base = wsb + OFF_W5T; }
  else if (i < 212992) { int t = i - 180224; n = t & 255; k2 = t >> 8; src = W6;     rs = 256; K = 256; nt16 = 16; base = wsb + OFF_W6T; }
  else if (i < 245760) { int t = i - 212992; n = t & 255; k2 = t >> 8; src = W7 + 1; rs = 257; K = 256; nt16 = 16; base = wsb + OFF_W7T; }
  else if (i < 262144) { int t = i - 245760; n = t & 127; k2 = t >> 7; src = Wc;     rs = 128; K = 256; nt16 = 8;  base = wsb + OFF_WCT; }
  else if (i < 262400) { int k = i - 262144; wsf[k] = W7[k * 257]; return; }
  else if (i < 262656) { int k = i - 262400; wsf[256 + k] = b7[k + 1]; return; }
  else return;
  const int k = k2 * 2;
  const float v0 = (k     < K) ? src[k * rs + n]       : 0.f;
  const float v1 = (k + 1 < K) ? src[(k + 1) * rs + n] : 0.f;
  const int off = ((k >> 5) * nt16 + (n >> 4)) * 512
                + ((k >> 3) & 3) * 128 + (n & 15) * 8 + (k & 7);
  const unsigned val = (unsigned)f2b(v0) | ((unsigned)f2b(v1) << 16);
  *(unsigned*)(base + off) = val;
}

// --- one layer: 2-D wave grid (wn 0..3, wm 0..1). Each wave: NT n-tiles
// (NT*16 neurons) x 2 m-tiles (32 pts). acc = 2*NT float4 = 32 AGPR (NT=4);
// fragments aC[4]+aN[4]+bfr[2] = 40 arch VGPRs -> ~88 unified, needs the
// (512,5) cap of 102 (R13 spilled at the (512,6) cap of 80).
// Burst = 8 MFMAs/k-step ~ 39 cyc: covers L2 A-latency at 4 waves/SIMD.
// Act-read amplification = 4 (vs 8 in R12): act LDS traffic halved.
template<int NT, int NTB, int KS1, int KS2, bool RELU>
__device__ __forceinline__ void layer_mm(
    const unsigned short* src1, const unsigned short* src2,
    const unsigned short* __restrict__ wT,
    const float* bias,
    unsigned short* dst, int lane, int wn, int wm)
{
  constexpr int KT = KS1 + KS2;
  const int c = lane & 15, q = lane >> 4;
  const int n0 = wn * (NT * 16);
  const unsigned short* wl = wT + (wn * NT) * 512 + lane * 8;

  float4_ acc[2][NT];
#pragma unroll
  for (int ni = 0; ni < NT; ++ni) {
    float4_ bv = *(const float4_*)(bias + n0 + ni * 16 + q * 4);
    acc[0][ni] = bv;
    acc[1][ni] = bv;
  }

  bf16x8 aC[NT], aN[NT];
#pragma unroll
  for (int ni = 0; ni < NT; ++ni) aC[ni] = *(const bf16x8*)(wl + ni * 512);

#pragma unroll
  for (int ks = 0; ks < KT; ++ks) {
    if (ks + 1 < KT) {   // prefetch next k-step's weight fragments first
#pragma unroll
      for (int ni = 0; ni < NT; ++ni)
        aN[ni] = *(const bf16x8*)(wl + ((ks + 1) * NTB + ni) * 512);
    }
    bf16x8 bfr[2];
#pragma unroll
    for (int m2 = 0; m2 < 2; ++m2) {
      const int mi = wm * 2 + m2;
      if (ks < KS1) {
        bfr[m2] = *(const bf16x8*)(src1 + (ks * 4 + mi) * 512 + lane * 8);
      } else {
        const int kse = ks - KS1;
        bf16x8 ev = *(const bf16x8*)(src2 + (mi * 16 + c) * 40 + kse * 32 + q * 8);
        bfr[m2] = (kse == 0 || q == 0) ? ev : bzero();
      }
    }
#pragma unroll
    for (int ni = 0; ni < NT; ++ni)
#pragma unroll
      for (int m2 = 0; m2 < 2; ++m2)
        acc[m2][ni] = __builtin_amdgcn_mfma_f32_16x16x32_bf16(
            aC[ni], bfr[m2], acc[m2][ni], 0, 0, 0);
    if (ks + 1 < KT) {
#pragma unroll
      for (int ni = 0; ni < NT; ++ni) aC[ni] = aN[ni];
    }
  }

  __syncthreads();   // all compute reads of sAct complete before overwrite
#pragma unroll
  for (int ni = 0; ni < NT; ++ni) {
    const int base = n0 + ni * 16 + q * 4;
#pragma unroll
    for (int m2 = 0; m2 < 2; ++m2) {
      const int mi = wm * 2 + m2;
      float4_ v = acc[m2][ni];
      if (RELU) {
        v.x = fmaxf(v.x, 0.f); v.y = fmaxf(v.y, 0.f);
        v.z = fmaxf(v.z, 0.f); v.w = fmaxf(v.w, 0.f);
      }
      const int addr = ((base >> 5) * 4 + mi) * 512
                     + ((base >> 3) & 3) * 128 + c * 8 + (base & 7);
      *(ushort4_*)(dst + addr) = pack4(v);
    }
  }
  __syncthreads();   // writes visible before next layer reads
}

// - fused NeRF fwd: 1 ray (64 pts)/block, 8 waves = 4 wn x 2 wm, (512,5) -
__global__ __launch_bounds__(512, 5) void nerf_kernel(
    const float* __restrict__ pts, const float* __restrict__ dirs,
    const float* __restrict__ b0, const float* __restrict__ b1,
    const float* __restrict__ b2, const float* __restrict__ b3,
    const float* __restrict__ b4, const float* __restrict__ b5,
    const float* __restrict__ b6, const float* __restrict__ b7,
    const float* __restrict__ Wc, const float* __restrict__ bc,
    const float* __restrict__ Wo, const float* __restrict__ bo,
    const unsigned short* __restrict__ wsb, const float* __restrict__ wsf,
    float* __restrict__ out)
{
  __shared__ __align__(16) unsigned short sAct[32 * 512];     // 32 KB
  __shared__ __align__(16) unsigned short sEmb[64 * 40 + 32]; // 5.2 KB
  __shared__ float s_dvec[27];
  __shared__ float s_biasc[128];

  const int ray = blockIdx.x;
  const int t = threadIdx.x;
  const int lane = t & 63;
  const int wave = t >> 6;
  const int wn = wave & 3, wm = wave >> 2;

  // xyz harmonic embedding -> compact sEmb rows of 40 cols (39 valid + 0 pad)
  {
    const int m = t >> 3, s8 = t & 7;          // point 0..63, col group 0..7
    const float* pb = pts + (ray * 64 + m) * 3;
    const float x0 = pb[0], x1 = pb[1], x2 = pb[2];
#pragma unroll
    for (int j = 0; j < 5; ++j) {
      const int cc = s8 * 5 + j;
      float v = 0.f;
      if (cc < 18) {
        const float xx = (cc < 6) ? x0 : (cc < 12) ? x1 : x2;
        v = sinf(xx * (float)(1 << (cc % 6)));
      } else if (cc < 36) {
        const int c2 = cc - 18;
        const float xx = (c2 < 6) ? x0 : (c2 < 12) ? x1 : x2;
        v = cosf(xx * (float)(1 << (c2 % 6)));
      } else if (cc == 36) v = x0;
      else if (cc == 37) v = x1;
      else if (cc == 38) v = x2;
      sEmb[m * 40 + cc] = f2b(v);
    }
  }
  if (t < 27) {   // direction harmonic embedding (ray-constant)
    const float* db = dirs + ray * 3;
    float v;
    if (t < 12) v = sinf(db[t >> 2] * (float)(1 << (t & 3)));
    else if (t < 24) { const int j2 = t - 12; v = cosf(db[j2 >> 2] * (float)(1 << (j2 & 3))); }
    else v = db[t - 24];
    s_dvec[t] = v;
  }
  __syncthreads();
  if (t < 128) {  // fold dir-embedding part of Wc into per-ray bias
    float s = bc[t];
#pragma unroll
    for (int j = 0; j < 27; ++j) s += s_dvec[j] * Wc[(256 + j) * 128 + t];
    s_biasc[t] = s;
  }
  // s_biasc writes are covered by layer0's internal barriers (read much later)

  // trunk
  layer_mm<4, 16, 0, 2, true >(sAct, sEmb, wsb + OFF_W0T, b0, sAct, lane, wn, wm);
  layer_mm<4, 16, 8, 0, true >(sAct, sEmb, wsb + OFF_W1T, b1, sAct, lane, wn, wm);
  layer_mm<4, 16, 8, 0, true >(sAct, sEmb, wsb + OFF_W2T, b2, sAct, lane, wn, wm);
  layer_mm<4, 16, 8, 0, true >(sAct, sEmb, wsb + OFF_W3T, b3, sAct, lane, wn, wm);
  layer_mm<4, 16, 8, 0, true >(sAct, sEmb, wsb + OFF_W4T, b4, sAct, lane, wn, wm);
  layer_mm<4, 16, 8, 2, true >(sAct, sEmb, wsb + OFF_W5T, b5, sAct, lane, wn, wm);  // skip concat
  layer_mm<4, 16, 8, 0, true >(sAct, sEmb, wsb + OFF_W6T, b6, sAct, lane, wn, wm);

  // sigma = relu(h6 . W7[:,0] + b7[0]); h6 in sAct (tile layout, 64 pts)
  {
    const int m = t >> 3, q8 = t & 7;
    float s = 0.f;
#pragma unroll
    for (int i8 = 0; i8 < 4; ++i8) {
      const int kb = q8 * 32 + i8 * 8;
      bf16x8 hv = *(const bf16x8*)(sAct + ((kb >> 5) * 4 + (m >> 4)) * 512
                                       + ((kb >> 3) & 3) * 128 + (m & 15) * 8);
      const float* w = wsf + kb;
#pragma unroll
      for (int j = 0; j < 8; ++j) s += (float)hv[j] * w[j];
    }
    s += __shfl_xor(s, 1); s += __shfl_xor(s, 2); s += __shfl_xor(s, 4);
    if (q8 == 0) out[393216 + ray * 64 + m] = fmaxf(s + b7[0], 0.f);
  }
  // sigma reads precede each thread's L7 compute; L7's internal barrier
  // precedes its writes -> no race.

  layer_mm<4, 16, 8, 0, false>(sAct, sEmb, wsb + OFF_W7T, wsf + 256, sAct, lane, wn, wm);
  // Wc: 128 outputs -> NT=2 (4 wn x 32 neurons), per-ray bias
  layer_mm<2, 8,  8, 0, true >(sAct, sEmb, wsb + OFF_WCT, s_biasc, sAct, lane, wn, wm);

  // color = sigmoid(c @ Wo + bo); c = 128 dims in sAct tiles 0..15
  {
    const int m = t >> 3, q8 = t & 7;
    float s0 = 0.f, s1 = 0.f, s2 = 0.f;
#pragma unroll
    for (int i2 = 0; i2 < 2; ++i2) {
      const int kb = q8 * 16 + i2 * 8;
      bf16x8 cv = *(const bf16x8*)(sAct + ((kb >> 5) * 4 + (m >> 4)) * 512
                                       + ((kb >> 3) & 3) * 128 + (m & 15) * 8);
#pragma unroll
      for (int j = 0; j < 8; ++j) {
        const float cc = (float)cv[j];
        const float* w = Wo + (kb + j) * 3;
        s0 += cc * w[0]; s1 += cc * w[1]; s2 += cc * w[2];
      }
    }
    s0 += __shfl_xor(s0, 1); s0 += __shfl_xor(s0, 2); s0 += __shfl_xor(s0, 4);
    s1 += __shfl_xor(s1, 1); s1 += __shfl_xor(s1, 2); s1 += __shfl_xor(s1, 4);
    s2 += __shfl_xor(s2, 1); s2 += __shfl_xor(s2, 2); s2 += __shfl_xor(s2, 4);
    if (q8 == 0) {
      float* oc = out + (ray * 64 + m) * 3;
      oc[0] = 1.f / (1.f + __expf(-(s0 + bo[0])));
      oc[1] = 1.f / (1.f + __expf(-(s1 + bo[1])));
      oc[2] = 1.f / (1.f + __expf(-(s2 + bo[2])));
    }
  }
}

extern "C" void kernel_launch(void* const* d_in, const int* in_sizes, int n_in,
                              void* d_out, int out_size, void* d_ws, size_t ws_size,
                              hipStream_t stream)
{
  const float* pts  = (const float*)d_in[0];
  const float* dirs = (const float*)d_in[1];
  const float* W0 = (const float*)d_in[2];   const float* b0 = (const float*)d_in[3];
  const float* W1 = (const float*)d_in[4];   const float* b1 = (const float*)d_in[5];
  const float* W2 = (const float*)d_in[6];   const float* b2 = (const float*)d_in[7];
  const float* W3 = (const float*)d_in[8];   const float* b3 = (const float*)d_in[9];
  const float* W4 = (const float*)d_in[10];  const float* b4 = (const float*)d_in[11];
  const float* W5 = (const float*)d_in[12];  const float* b5 = (const float*)d_in[13];
  const float* W6 = (const float*)d_in[14];  const float* b6 = (const float*)d_in[15];
  const float* W7 = (const float*)d_in[16];  const float* b7 = (const float*)d_in[17];
  const float* Wc = (const float*)d_in[18];  const float* bc = (const float*)d_in[19];
  const float* Wo = (const float*)d_in[20];  const float* bo = (const float*)d_in[21];

  unsigned short* wsb = (unsigned short*)d_ws;
  float* wsf = (float*)((char*)d_ws + WSF_BYTE_OFF);

  prep_kernel<<<1026, 256, 0, stream>>>(W0, W1, W2, W3, W4, W5, W6, W7, Wc, b7, wsb, wsf);
  nerf_kernel<<<2048, 512, 0, stream>>>(pts, dirs, b0, b1, b2, b3, b4, b5, b6, b7,
                                        Wc, bc, Wo, bo, wsb, wsf, (float*)d_out);
}

// Round 16
// 268.215 us; speedup vs baseline: 1.0826x; 1.0826x over previous
//
#include <hip/hip_runtime.h>

typedef __attribute__((ext_vector_type(8))) __bf16 bf16x8;
typedef __attribute__((ext_vector_type(4))) float float4_;
typedef __attribute__((ext_vector_type(4))) unsigned short ushort4_;
typedef __attribute__((ext_vector_type(8))) unsigned short ushort8_;

// Weights stored as packed MFMA A-fragment tiles of 512 bf16, order [kt][ntile].
// Activations in LDS as B-fragment tiles, order [kt][mtile] (4 m-tiles = 64 pts).
// elem (n|pt, k) within tile: ((k>>3)&3)*128 + (n&15)*8 + (k&7)
// -> every wave fragment access is base + lane*16B: coalesced / 2-way-free banks.
#define OFF_W0T 0        // Kp=64  (KT=2),  NTB=16
#define OFF_W1T 16384    // Kp=256 x4,      NTB=16
#define OFF_W2T 81920
#define OFF_W3T 147456
#define OFF_W4T 212992
#define OFF_W5T 278528   // Kp=320 (KT=10), NTB=16
#define OFF_W6T 360448
#define OFF_W7T 425984   // W7[:,1:257]
#define OFF_WCT 491520   // N=128 -> NTB=8, Kp=256
#define BF16_TOTAL 524288
#define WSF_BYTE_OFF (BF16_TOTAL * 2)  // f32: w7sig[256], b7a[256]

__device__ __forceinline__ unsigned short f2b(float v) {
  union { float f; unsigned u; } a; a.f = v;
  unsigned r = a.u + 0x7fffu + ((a.u >> 16) & 1u);
  return (unsigned short)(r >> 16);
}

__device__ __forceinline__ bf16x8 bzero() {
  union { ushort8_ u; bf16x8 b; } z;
  ushort8_ t = {0, 0, 0, 0, 0, 0, 0, 0};
  z.u = t;
  return z.b;
}

// 4x f32 -> 4x bf16 (RNE) via gfx950 packed cvt when available.
__device__ __forceinline__ ushort4_ pack4(float4_ v) {
#if __has_builtin(__builtin_amdgcn_cvt_pk_bf16_f32)
  auto p0 = __builtin_amdgcn_cvt_pk_bf16_f32(v.x, v.y);
  auto p1 = __builtin_amdgcn_cvt_pk_bf16_f32(v.z, v.w);
  union { decltype(p0) p; unsigned u; } u0, u1;
  u0.p = p0; u1.p = p1;
  ushort4_ r;
  r.x = (unsigned short)(u0.u & 0xffffu); r.y = (unsigned short)(u0.u >> 16);
  r.z = (unsigned short)(u1.u & 0xffffu); r.w = (unsigned short)(u1.u >> 16);
  return r;
#else
  ushort4_ r; r.x = f2b(v.x); r.y = f2b(v.y); r.z = f2b(v.z); r.w = f2b(v.w);
  return r;
#endif
}

// ---------------- weight prep: coalesced reads, MFMA-tile packed ----------
__global__ __launch_bounds__(256) void prep_kernel(
    const float* __restrict__ W0, const float* __restrict__ W1,
    const float* __restrict__ W2, const float* __restrict__ W3,
    const float* __restrict__ W4, const float* __restrict__ W5,
    const float* __restrict__ W6, const float* __restrict__ W7,
    const float* __restrict__ Wc, const float* __restrict__ b7,
    unsigned short* __restrict__ wsb, float* __restrict__ wsf)
{
  int i = blockIdx.x * 256 + threadIdx.x;
  const float* src; int rs, K, n, k2, nt16; unsigned short* base;
  if (i < 8192)        { int t = i;          n = t & 255; k2 = t >> 8; src = W0; rs = 256; K = 39;  nt16 = 16; base = wsb + OFF_W0T; }
  else if (i < 139264) { int t = i - 8192;   int l = t >> 15; t &= 32767;
                         n = t & 255; k2 = t >> 8;
                         src = (l == 0) ? W1 : (l == 1) ? W2 : (l == 2) ? W3 : W4;
                         rs = 256; K = 256; nt16 = 16; base = wsb + OFF_W1T + l * 65536; }
  else if (i < 180224) { int t = i - 139264; n = t & 255; k2 = t >> 8; src = W5;     rs = 256; K = 295; nt16 = 16; base = wsb + OFF_W5T; }
  else if (i < 212992) { int t = i - 180224; n = t & 255; k2 = t >> 8; src = W6;     rs = 256; K = 256; nt16 = 16; base = wsb + OFF_W6T; }
  else if (i < 245760) { int t = i - 212992; n = t & 255; k2 = t >> 8; src = W7 + 1; rs = 257; K = 256; nt16 = 16; base = wsb + OFF_W7T; }
  else if (i < 262144) { int t = i - 245760; n = t & 127; k2 = t >> 7; src = Wc;     rs = 128; K = 256; nt16 = 8;  base = wsb + OFF_WCT; }
  else if (i < 262400) { int k = i - 262144; wsf[k] = W7[k * 257]; return; }
  else if (i < 262656) { int k = i - 262400; wsf[256 + k] = b7[k + 1]; return; }
  else return;
  const int k = k2 * 2;
  const float v0 = (k     < K) ? src[k * rs + n]       : 0.f;
  const float v1 = (k + 1 < K) ? src[(k + 1) * rs + n] : 0.f;
  const int off = ((k >> 5) * nt16 + (n >> 4)) * 512
                + ((k >> 3) & 3) * 128 + (n & 15) * 8 + (k & 7);
  const unsigned val = (unsigned)f2b(v0) | ((unsigned)f2b(v1) << 16);
  *(unsigned*)(base + off) = val;
}

// --- one layer: 64 pts (1 ray) x (NT*16) neurons per wave, swapped MFMA ---
// R12 shape. No explicit A-prefetch regs: the unrolled loop lets the compiler
// pipeline within the 64-reg budget of 8 waves/SIMD; blocking-load exposure
// is covered by TLP (7 co-resident waves x ~39cyc burst > 200cyc L2 latency).
// Single shared act buffer: compute (reads) -> barrier -> write -> barrier.
template<int NT, int NTB, int KS1, int KS2, bool RELU>
__device__ __forceinline__ void layer_mm(
    const unsigned short* src1, const unsigned short* src2,
    const unsigned short* __restrict__ wT,
    const float* bias,
    unsigned short* dst, int lane, int wave)
{
  constexpr int KT = KS1 + KS2;
  const int c = lane & 15, q = lane >> 4;
  const int n0 = wave * (NT * 16);
  const unsigned short* wl = wT + (wave * NT) * 512 + lane * 8;

  float4_ acc[4][NT];
#pragma unroll
  for (int ni = 0; ni < NT; ++ni) {
    float4_ bv = *(const float4_*)(bias + n0 + ni * 16 + q * 4);
#pragma unroll
    for (int m4 = 0; m4 < 4; ++m4) acc[m4][ni] = bv;
  }

#pragma unroll
  for (int ks = 0; ks < KT; ++ks) {
    bf16x8 aC[NT];
#pragma unroll
    for (int ni = 0; ni < NT; ++ni)
      aC[ni] = *(const bf16x8*)(wl + (ks * NTB + ni) * 512);
#pragma unroll
    for (int mh = 0; mh < 2; ++mh) {   // 2 chunks of 2 m-tiles (low VGPR)
      bf16x8 bfr[2];
#pragma unroll
      for (int m2 = 0; m2 < 2; ++m2) {
        const int mi = mh * 2 + m2;
        if (ks < KS1) {
          bfr[m2] = *(const bf16x8*)(src1 + (ks * 4 + mi) * 512 + lane * 8);
        } else {
          const int kse = ks - KS1;
          bf16x8 ev = *(const bf16x8*)(src2 + (mi * 16 + c) * 40 + kse * 32 + q * 8);
          bfr[m2] = (kse == 0 || q == 0) ? ev : bzero();
        }
      }
#pragma unroll
      for (int ni = 0; ni < NT; ++ni)
#pragma unroll
        for (int m2 = 0; m2 < 2; ++m2)
          acc[mh * 2 + m2][ni] = __builtin_amdgcn_mfma_f32_16x16x32_bf16(
              aC[ni], bfr[m2], acc[mh * 2 + m2][ni], 0, 0, 0);
    }
  }

  __syncthreads();   // all compute reads of sAct complete before overwrite
#pragma unroll
  for (int ni = 0; ni < NT; ++ni) {
    const int base = n0 + ni * 16 + q * 4;
#pragma unroll
    for (int m4 = 0; m4 < 4; ++m4) {
      float4_ v = acc[m4][ni];
      if (RELU) {
        v.x = fmaxf(v.x, 0.f); v.y = fmaxf(v.y, 0.f);
        v.z = fmaxf(v.z, 0.f); v.w = fmaxf(v.w, 0.f);
      }
      const int addr = ((base >> 5) * 4 + m4) * 512
                     + ((base >> 3) & 3) * 128 + c * 8 + (base & 7);
      *(ushort4_*)(dst + addr) = pack4(v);
    }
  }
  __syncthreads();   // writes visible before next layer reads
}

// - fused NeRF fwd: 1 ray (64 pts)/block, 8 waves x 32 neurons, 4 blocks/CU -
__global__ __launch_bounds__(512, 8) void nerf_kernel(
    const float* __restrict__ pts, const float* __restrict__ dirs,
    const float* __restrict__ b0, const float* __restrict__ b1,
    const float* __restrict__ b2, const float* __restrict__ b3,
    const float* __restrict__ b4, const float* __restrict__ b5,
    const float* __restrict__ b6, const float* __restrict__ b7,
    const float* __restrict__ Wc, const float* __restrict__ bc,
    const float* __restrict__ Wo, const float* __restrict__ bo,
    const unsigned short* __restrict__ wsb, const float* __restrict__ wsf,
    float* __restrict__ out)
{
  __shared__ __align__(16) unsigned short sAct[32 * 512];     // 32 KB
  __shared__ __align__(16) unsigned short sEmb[64 * 40 + 32]; // 5.2 KB
  __shared__ float s_dvec[27];
  __shared__ float s_biasc[128];

  const int ray = blockIdx.x;
  const int t = threadIdx.x;
  const int lane = t & 63;
  const int wave = t >> 6;

  // xyz harmonic embedding -> compact sEmb rows of 40 cols (39 valid + 0 pad)
  {
    const int m = t >> 3, s8 = t & 7;          // point 0..63, col group 0..7
    const float* pb = pts + (ray * 64 + m) * 3;
    const float x0 = pb[0], x1 = pb[1], x2 = pb[2];
#pragma unroll
    for (int j = 0; j < 5; ++j) {
      const int cc = s8 * 5 + j;
      float v = 0.f;
      if (cc < 18) {
        const float xx = (cc < 6) ? x0 : (cc < 12) ? x1 : x2;
        v = sinf(xx * (float)(1 << (cc % 6)));
      } else if (cc < 36) {
        const int c2 = cc - 18;
        const float xx = (c2 < 6) ? x0 : (c2 < 12) ? x1 : x2;
        v = cosf(xx * (float)(1 << (c2 % 6)));
      } else if (cc == 36) v = x0;
      else if (cc == 37) v = x1;
      else if (cc == 38) v = x2;
      sEmb[m * 40 + cc] = f2b(v);
    }
  }
  if (t < 27) {   // direction harmonic embedding (ray-constant)
    const float* db = dirs + ray * 3;
    float v;
    if (t < 12) v = sinf(db[t >> 2] * (float)(1 << (t & 3)));
    else if (t < 24) { const int j2 = t - 12; v = cosf(db[j2 >> 2] * (float)(1 << (j2 & 3))); }
    else v = db[t - 24];
    s_dvec[t] = v;
  }
  __syncthreads();
  if (t < 128) {  // fold dir-embedding part of Wc into per-ray bias
    float s = bc[t];
#pragma unroll
    for (int j = 0; j < 27; ++j) s += s_dvec[j] * Wc[(256 + j) * 128 + t];
    s_biasc[t] = s;
  }
  // s_biasc writes are covered by layer0's internal barriers (read much later)

  // trunk
  layer_mm<2, 16, 0, 2, true >(sAct, sEmb, wsb + OFF_W0T, b0, sAct, lane, wave);
  layer_mm<2, 16, 8, 0, true >(sAct, sEmb, wsb + OFF_W1T, b1, sAct, lane, wave);
  layer_mm<2, 16, 8, 0, true >(sAct, sEmb, wsb + OFF_W2T, b2, sAct, lane, wave);
  layer_mm<2, 16, 8, 0, true >(sAct, sEmb, wsb + OFF_W3T, b3, sAct, lane, wave);
  layer_mm<2, 16, 8, 0, true >(sAct, sEmb, wsb + OFF_W4T, b4, sAct, lane, wave);
  layer_mm<2, 16, 8, 2, true >(sAct, sEmb, wsb + OFF_W5T, b5, sAct, lane, wave);  // skip concat
  layer_mm<2, 16, 8, 0, true >(sAct, sEmb, wsb + OFF_W6T, b6, sAct, lane, wave);

  // sigma = relu(h6 . W7[:,0] + b7[0]); h6 in sAct (tile layout, 64 pts)
  {
    const int m = t >> 3, q8 = t & 7;
    float s = 0.f;
#pragma unroll
    for (int i8 = 0; i8 < 4; ++i8) {
      const int kb = q8 * 32 + i8 * 8;
      bf16x8 hv = *(const bf16x8*)(sAct + ((kb >> 5) * 4 + (m >> 4)) * 512
                                       + ((kb >> 3) & 3) * 128 + (m & 15) * 8);
      const float* w = wsf + kb;
#pragma unroll
      for (int j = 0; j < 8; ++j) s += (float)hv[j] * w[j];
    }
    s += __shfl_xor(s, 1); s += __shfl_xor(s, 2); s += __shfl_xor(s, 4);
    if (q8 == 0) out[393216 + ray * 64 + m] = fmaxf(s + b7[0], 0.f);
  }
  // sigma reads precede each thread's L7 compute; L7's internal barrier
  // precedes its writes -> no race.

  layer_mm<2, 16, 8, 0, false>(sAct, sEmb, wsb + OFF_W7T, wsf + 256, sAct, lane, wave);
  // Wc: 128 outputs -> NT=1 (8 waves x 16 neurons), per-ray bias
  layer_mm<1, 8,  8, 0, true >(sAct, sEmb, wsb + OFF_WCT, s_biasc, sAct, lane, wave);

  // color = sigmoid(c @ Wo + bo); c = 128 dims in sAct tiles 0..15
  {
    const int m = t >> 3, q8 = t & 7;
    float s0 = 0.f, s1 = 0.f, s2 = 0.f;
#pragma unroll
    for (int i2 = 0; i2 < 2; ++i2) {
      const int kb = q8 * 16 + i2 * 8;
      bf16x8 cv = *(const bf16x8*)(sAct + ((kb >> 5) * 4 + (m >> 4)) * 512
                                       + ((kb >> 3) & 3) * 128 + (m & 15) * 8);
#pragma unroll
      for (int j = 0; j < 8; ++j) {
        const float cc = (float)cv[j];
        const float* w = Wo + (kb + j) * 3;
        s0 += cc * w[0]; s1 += cc * w[1]; s2 += cc * w[2];
      }
    }
    s0 += __shfl_xor(s0, 1); s0 += __shfl_xor(s0, 2); s0 += __shfl_xor(s0, 4);
    s1 += __shfl_xor(s1, 1); s1 += __shfl_xor(s1, 2); s1 += __shfl_xor(s1, 4);
    s2 += __shfl_xor(s2, 1); s2 += __shfl_xor(s2, 2); s2 += __shfl_xor(s2, 4);
    if (q8 == 0) {
      float* oc = out + (ray * 64 + m) * 3;
      oc[0] = 1.f / (1.f + __expf(-(s0 + bo[0])));
      oc[1] = 1.f / (1.f + __expf(-(s1 + bo[1])));
      oc[2] = 1.f / (1.f + __expf(-(s2 + bo[2])));
    }
  }
}

extern "C" void kernel_launch(void* const* d_in, const int* in_sizes, int n_in,
                              void* d_out, int out_size, void* d_ws, size_t ws_size,
                              hipStream_t stream)
{
  const float* pts  = (const float*)d_in[0];
  const float* dirs = (const float*)d_in[1];
  const float* W0 = (const float*)d_in[2];   const float* b0 = (const float*)d_in[3];
  const float* W1 = (const float*)d_in[4];   const float* b1 = (const float*)d_in[5];
  const float* W2 = (const float*)d_in[6];   const float* b2 = (const float*)d_in[7];
  const float* W3 = (const float*)d_in[8];   const float* b3 = (const float*)d_in[9];
  const float* W4 = (const float*)d_in[10];  const float* b4 = (const float*)d_in[11];
  const float* W5 = (const float*)d_in[12];  const float* b5 = (const float*)d_in[13];
  const float* W6 = (const float*)d_in[14];  const float* b6 = (const float*)d_in[15];
  const float* W7 = (const float*)d_in[16];  const float* b7 = (const float*)d_in[17];
  const float* Wc = (const float*)d_in[18];  const float* bc = (const float*)d_in[19];
  const float* Wo = (const float*)d_in[20];  const float* bo = (const float*)d_in[21];

  unsigned short* wsb = (unsigned short*)d_ws;
  float* wsf = (float*)((char*)d_ws + WSF_BYTE_OFF);

  prep_kernel<<<1026, 256, 0, stream>>>(W0, W1, W2, W3, W4, W5, W6, W7, Wc, b7, wsb, wsf);
  nerf_kernel<<<2048, 512, 0, stream>>>(pts, dirs, b0, b1, b2, b3, b4, b5, b6, b7,
                                        Wc, bc, Wo, bo, wsb, wsf, (float*)d_out);
}

// Round 17
// 239.397 us; speedup vs baseline: 1.2129x; 1.1204x over previous
//
#include <hip/hip_runtime.h>

typedef __attribute__((ext_vector_type(8))) __bf16 bf16x8;
typedef __attribute__((ext_vector_type(4))) float float4_;
typedef __attribute__((ext_vector_type(4))) unsigned short ushort4_;
typedef __attribute__((ext_vector_type(8))) unsigned short ushort8_;

// Weights stored as packed MFMA A-fragment tiles of 512 bf16, order [kt][ntile].
// Activations in LDS as B-fragment tiles, order [kt][mtile] (4 m-tiles = 64 pts).
// elem (n|pt, k) within tile: ((k>>3)&3)*128 + (n&15)*8 + (k&7)
// -> every wave fragment access is base + lane*16B: coalesced / 2-way-free banks.
#define OFF_W0T 0        // Kp=64  (KT=2),  NTB=16
#define OFF_W1T 16384    // Kp=256 x4,      NTB=16
#define OFF_W2T 81920
#define OFF_W3T 147456
#define OFF_W4T 212992
#define OFF_W5T 278528   // Kp=320 (KT=10), NTB=16
#define OFF_W6T 360448
#define OFF_W7T 425984   // W7[:,1:257]
#define OFF_WCT 491520   // N=128 -> NTB=8, Kp=256
#define BF16_TOTAL 524288
#define WSF_BYTE_OFF (BF16_TOTAL * 2)  // f32: w7sig[256], b7a[256]

__device__ __forceinline__ unsigned short f2b(float v) {
  union { float f; unsigned u; } a; a.f = v;
  unsigned r = a.u + 0x7fffu + ((a.u >> 16) & 1u);
  return (unsigned short)(r >> 16);
}

__device__ __forceinline__ bf16x8 bzero() {
  union { ushort8_ u; bf16x8 b; } z;
  ushort8_ t = {0, 0, 0, 0, 0, 0, 0, 0};
  z.u = t;
  return z.b;
}

// 4x f32 -> 4x bf16 (RNE) via gfx950 packed cvt when available.
__device__ __forceinline__ ushort4_ pack4(float4_ v) {
#if __has_builtin(__builtin_amdgcn_cvt_pk_bf16_f32)
  auto p0 = __builtin_amdgcn_cvt_pk_bf16_f32(v.x, v.y);
  auto p1 = __builtin_amdgcn_cvt_pk_bf16_f32(v.z, v.w);
  union { decltype(p0) p; unsigned u; } u0, u1;
  u0.p = p0; u1.p = p1;
  ushort4_ r;
  r.x = (unsigned short)(u0.u & 0xffffu); r.y = (unsigned short)(u0.u >> 16);
  r.z = (unsigned short)(u1.u & 0xffffu); r.w = (unsigned short)(u1.u >> 16);
  return r;
#else
  ushort4_ r; r.x = f2b(v.x); r.y = f2b(v.y); r.z = f2b(v.z); r.w = f2b(v.w);
  return r;
#endif
}

// ---------------- weight prep: coalesced reads, MFMA-tile packed ----------
__global__ __launch_bounds__(256) void prep_kernel(
    const float* __restrict__ W0, const float* __restrict__ W1,
    const float* __restrict__ W2, const float* __restrict__ W3,
    const float* __restrict__ W4, const float* __restrict__ W5,
    const float* __restrict__ W6, const float* __restrict__ W7,
    const float* __restrict__ Wc, const float* __restrict__ b7,
    unsigned short* __restrict__ wsb, float* __restrict__ wsf)
{
  int i = blockIdx.x * 256 + threadIdx.x;
  const float* src; int rs, K, n, k2, nt16; unsigned short* base;
  if (i < 8192)        { int t = i;          n = t & 255; k2 = t >> 8; src = W0; rs = 256; K = 39;  nt16 = 16; base = wsb + OFF_W0T; }
  else if (i < 139264) { int t = i - 8192;   int l = t >> 15; t &= 32767;
                         n = t & 255; k2 = t >> 8;
                         src = (l == 0) ? W1 : (l == 1) ? W2 : (l == 2) ? W3 : W4;
                         rs = 256; K = 256; nt16 = 16; base = wsb + OFF_W1T + l * 65536; }
  else if (i < 180224) { int t = i - 139264; n = t & 255; k2 = t >> 8; src = W5;     rs = 256; K = 295; nt16 = 16; base = wsb + OFF_W5T; }
  else if (i < 212992) { int t = i - 180224; n = t & 255; k2 = t >> 8; src = W6;     rs = 256; K = 256; nt16 = 16; base = wsb + OFF_W6T; }
  else if (i < 245760) { int t = i - 212992; n = t & 255; k2 = t >> 8; src = W7 + 1; rs = 257; K = 256; nt16 = 16; base = wsb + OFF_W7T; }
  else if (i < 262144) { int t = i - 245760; n = t & 127; k2 = t >> 7; src = Wc;     rs = 128; K = 256; nt16 = 8;  base = wsb + OFF_WCT; }
  else if (i < 262400) { int k = i - 262144; wsf[k] = W7[k * 257]; return; }
  else if (i < 262656) { int k = i - 262400; wsf[256 + k] = b7[k + 1]; return; }
  else return;
  const int k = k2 * 2;
  const float v0 = (k     < K) ? src[k * rs + n]       : 0.f;
  const float v1 = (k + 1 < K) ? src[(k + 1) * rs + n] : 0.f;
  const int off = ((k >> 5) * nt16 + (n >> 4)) * 512
                + ((k >> 3) & 3) * 128 + (n & 15) * 8 + (k & 7);
  const unsigned val = (unsigned)f2b(v0) | ((unsigned)f2b(v1) << 16);
  *(unsigned*)(base + off) = val;
}

// --- one layer: 64 pts (1 ray) x (NT*16) neurons per wave, swapped MFMA ---
// acc = 4 m-tiles x NT<=2 = 32 AGPR; aC/aN prefetch one k-step ahead covers
// L2 A-latency together with 24 waves/CU TLP. 72 unified regs fits the
// (512,6) cap of 80 — the unique spill-free high-TLP corner (R7..R16 map).
// Single shared act buffer: compute (reads) -> barrier -> write -> barrier.
template<int NT, int NTB, int KS1, int KS2, bool RELU>
__device__ __forceinline__ void layer_mm(
    const unsigned short* src1, const unsigned short* src2,
    const unsigned short* __restrict__ wT,
    const float* bias,
    unsigned short* dst, int lane, int wave)
{
  constexpr int KT = KS1 + KS2;
  const int c = lane & 15, q = lane >> 4;
  const int n0 = wave * (NT * 16);
  const unsigned short* wl = wT + (wave * NT) * 512 + lane * 8;

  float4_ acc[4][NT];
#pragma unroll
  for (int ni = 0; ni < NT; ++ni) {
    float4_ bv = *(const float4_*)(bias + n0 + ni * 16 + q * 4);
#pragma unroll
    for (int m4 = 0; m4 < 4; ++m4) acc[m4][ni] = bv;
  }

  bf16x8 aC[NT], aN[NT];
#pragma unroll
  for (int ni = 0; ni < NT; ++ni) aC[ni] = *(const bf16x8*)(wl + ni * 512);

#pragma unroll
  for (int ks = 0; ks < KT; ++ks) {
    if (ks + 1 < KT) {   // prefetch next k-step's weight fragments first
#pragma unroll
      for (int ni = 0; ni < NT; ++ni)
        aN[ni] = *(const bf16x8*)(wl + ((ks + 1) * NTB + ni) * 512);
    }
#pragma unroll
    for (int mh = 0; mh < 2; ++mh) {   // 2 chunks of 2 m-tiles (low VGPR)
      bf16x8 bfr[2];
#pragma unroll
      for (int m2 = 0; m2 < 2; ++m2) {
        const int mi = mh * 2 + m2;
        if (ks < KS1) {
          bfr[m2] = *(const bf16x8*)(src1 + (ks * 4 + mi) * 512 + lane * 8);
        } else {
          const int kse = ks - KS1;
          bf16x8 ev = *(const bf16x8*)(src2 + (mi * 16 + c) * 40 + kse * 32 + q * 8);
          bfr[m2] = (kse == 0 || q == 0) ? ev : bzero();
        }
      }
#pragma unroll
      for (int ni = 0; ni < NT; ++ni)
#pragma unroll
        for (int m2 = 0; m2 < 2; ++m2)
          acc[mh * 2 + m2][ni] = __builtin_amdgcn_mfma_f32_16x16x32_bf16(
              aC[ni], bfr[m2], acc[mh * 2 + m2][ni], 0, 0, 0);
    }
    if (ks + 1 < KT) {
#pragma unroll
      for (int ni = 0; ni < NT; ++ni) aC[ni] = aN[ni];
    }
  }

  __syncthreads();   // all compute reads of sAct complete before overwrite
#pragma unroll
  for (int ni = 0; ni < NT; ++ni) {
    const int base = n0 + ni * 16 + q * 4;
#pragma unroll
    for (int m4 = 0; m4 < 4; ++m4) {
      float4_ v = acc[m4][ni];
      if (RELU) {
        v.x = fmaxf(v.x, 0.f); v.y = fmaxf(v.y, 0.f);
        v.z = fmaxf(v.z, 0.f); v.w = fmaxf(v.w, 0.f);
      }
      const int addr = ((base >> 5) * 4 + m4) * 512
                     + ((base >> 3) & 3) * 128 + c * 8 + (base & 7);
      *(ushort4_*)(dst + addr) = pack4(v);
    }
  }
  __syncthreads();   // writes visible before next layer reads
}

// - fused NeRF fwd: 1 ray (64 pts)/block, 8 waves x 32 neurons, 3 blocks/CU -
__global__ __launch_bounds__(512, 6) void nerf_kernel(
    const float* __restrict__ pts, const float* __restrict__ dirs,
    const float* __restrict__ b0, const float* __restrict__ b1,
    const float* __restrict__ b2, const float* __restrict__ b3,
    const float* __restrict__ b4, const float* __restrict__ b5,
    const float* __restrict__ b6, const float* __restrict__ b7,
    const float* __restrict__ Wc, const float* __restrict__ bc,
    const float* __restrict__ Wo, const float* __restrict__ bo,
    const unsigned short* __restrict__ wsb, const float* __restrict__ wsf,
    float* __restrict__ out)
{
  __shared__ __align__(16) unsigned short sAct[32 * 512];     // 32 KB
  __shared__ __align__(16) unsigned short sEmb[64 * 40 + 32]; // 5.2 KB
  __shared__ float s_dvec[27];
  __shared__ float s_biasc[128];

  const int ray = blockIdx.x;
  const int t = threadIdx.x;
  const int lane = t & 63;
  const int wave = t >> 6;

  // xyz harmonic embedding -> compact sEmb rows of 40 cols (39 valid + 0 pad)
  {
    const int m = t >> 3, s8 = t & 7;          // point 0..63, col group 0..7
    const float* pb = pts + (ray * 64 + m) * 3;
    const float x0 = pb[0], x1 = pb[1], x2 = pb[2];
#pragma unroll
    for (int j = 0; j < 5; ++j) {
      const int cc = s8 * 5 + j;
      float v = 0.f;
      if (cc < 18) {
        const float xx = (cc < 6) ? x0 : (cc < 12) ? x1 : x2;
        v = sinf(xx * (float)(1 << (cc % 6)));
      } else if (cc < 36) {
        const int c2 = cc - 18;
        const float xx = (c2 < 6) ? x0 : (c2 < 12) ? x1 : x2;
        v = cosf(xx * (float)(1 << (c2 % 6)));
      } else if (cc == 36) v = x0;
      else if (cc == 37) v = x1;
      else if (cc == 38) v = x2;
      sEmb[m * 40 + cc] = f2b(v);
    }
  }
  if (t < 27) {   // direction harmonic embedding (ray-constant)
    const float* db = dirs + ray * 3;
    float v;
    if (t < 12) v = sinf(db[t >> 2] * (float)(1 << (t & 3)));
    else if (t < 24) { const int j2 = t - 12; v = cosf(db[j2 >> 2] * (float)(1 << (j2 & 3))); }
    else v = db[t - 24];
    s_dvec[t] = v;
  }
  __syncthreads();
  if (t < 128) {  // fold dir-embedding part of Wc into per-ray bias
    float s = bc[t];
#pragma unroll
    for (int j = 0; j < 27; ++j) s += s_dvec[j] * Wc[(256 + j) * 128 + t];
    s_biasc[t] = s;
  }
  // s_biasc writes are covered by layer0's internal barriers (read much later)

  // trunk
  layer_mm<2, 16, 0, 2, true >(sAct, sEmb, wsb + OFF_W0T, b0, sAct, lane, wave);
  layer_mm<2, 16, 8, 0, true >(sAct, sEmb, wsb + OFF_W1T, b1, sAct, lane, wave);
  layer_mm<2, 16, 8, 0, true >(sAct, sEmb, wsb + OFF_W2T, b2, sAct, lane, wave);
  layer_mm<2, 16, 8, 0, true >(sAct, sEmb, wsb + OFF_W3T, b3, sAct, lane, wave);
  layer_mm<2, 16, 8, 0, true >(sAct, sEmb, wsb + OFF_W4T, b4, sAct, lane, wave);
  layer_mm<2, 16, 8, 2, true >(sAct, sEmb, wsb + OFF_W5T, b5, sAct, lane, wave);  // skip concat
  layer_mm<2, 16, 8, 0, true >(sAct, sEmb, wsb + OFF_W6T, b6, sAct, lane, wave);

  // sigma = relu(h6 . W7[:,0] + b7[0]); h6 in sAct (tile layout, 64 pts)
  {
    const int m = t >> 3, q8 = t & 7;
    float s = 0.f;
#pragma unroll
    for (int i8 = 0; i8 < 4; ++i8) {
      const int kb = q8 * 32 + i8 * 8;
      bf16x8 hv = *(const bf16x8*)(sAct + ((kb >> 5) * 4 + (m >> 4)) * 512
                                       + ((kb >> 3) & 3) * 128 + (m & 15) * 8);
      const float* w = wsf + kb;
#pragma unroll
      for (int j = 0; j < 8; ++j) s += (float)hv[j] * w[j];
    }
    s += __shfl_xor(s, 1); s += __shfl_xor(s, 2); s += __shfl_xor(s, 4);
    if (q8 == 0) out[393216 + ray * 64 + m] = fmaxf(s + b7[0], 0.f);
  }
  // sigma reads precede each thread's L7 compute; L7's internal barrier
  // precedes its writes -> no race.

  layer_mm<2, 16, 8, 0, false>(sAct, sEmb, wsb + OFF_W7T, wsf + 256, sAct, lane, wave);
  // Wc: 128 outputs -> NT=1 (8 waves x 16 neurons), per-ray bias
  layer_mm<1, 8,  8, 0, true >(sAct, sEmb, wsb + OFF_WCT, s_biasc, sAct, lane, wave);

  // color = sigmoid(c @ Wo + bo); c = 128 dims in sAct tiles 0..15
  {
    const int m = t >> 3, q8 = t & 7;
    float s0 = 0.f, s1 = 0.f, s2 = 0.f;
#pragma unroll
    for (int i2 = 0; i2 < 2; ++i2) {
      const int kb = q8 * 16 + i2 * 8;
      bf16x8 cv = *(const bf16x8*)(sAct + ((kb >> 5) * 4 + (m >> 4)) * 512
                                       + ((kb >> 3) & 3) * 128 + (m & 15) * 8);
#pragma unroll
      for (int j = 0; j < 8; ++j) {
        const float cc = (float)cv[j];
        const float* w = Wo + (kb + j) * 3;
        s0 += cc * w[0]; s1 += cc * w[1]; s2 += cc * w[2];
      }
    }
    s0 += __shfl_xor(s0, 1); s0 += __shfl_xor(s0, 2); s0 += __shfl_xor(s0, 4);
    s1 += __shfl_xor(s1, 1); s1 += __shfl_xor(s1, 2); s1 += __shfl_xor(s1, 4);
    s2 += __shfl_xor(s2, 1); s2 += __shfl_xor(s2, 2); s2 += __shfl_xor(s2, 4);
    if (q8 == 0) {
      float* oc = out + (ray * 64 + m) * 3;
      oc[0] = 1.f / (1.f + __expf(-(s0 + bo[0])));
      oc[1] = 1.f / (1.f + __expf(-(s1 + bo[1])));
      oc[2] = 1.f / (1.f + __expf(-(s2 + bo[2])));
    }
  }
}

extern "C" void kernel_launch(void* const* d_in, const int* in_sizes, int n_in,
                              void* d_out, int out_size, void* d_ws, size_t ws_size,
                              hipStream_t stream)
{
  const float* pts  = (const float*)d_in[0];
  const float* dirs = (const float*)d_in[1];
  const float* W0 = (const float*)d_in[2];   const float* b0 = (const float*)d_in[3];
  const float* W1 = (const float*)d_in[4];   const float* b1 = (const float*)d_in[5];
  const float* W2 = (const float*)d_in[6];   const float* b2 = (const float*)d_in[7];
  const float* W3 = (const float*)d_in[8];   const float* b3 = (const float*)d_in[9];
  const float* W4 = (const float*)d_in[10];  const float* b4 = (const float*)d_in[11];
  const float* W5 = (const float*)d_in[12];  const float* b5 = (const float*)d_in[13];
  const float* W6 = (const float*)d_in[14];  const float* b6 = (const float*)d_in[15];
  const float* W7 = (const float*)d_in[16];  const float* b7 = (const float*)d_in[17];
  const float* Wc = (const float*)d_in[18];  const float* bc = (const float*)d_in[19];
  const float* Wo = (const float*)d_in[20];  const float* bo = (const float*)d_in[21];

  unsigned short* wsb = (unsigned short*)d_ws;
  float* wsf = (float*)((char*)d_ws + WSF_BYTE_OFF);

  prep_kernel<<<1026, 256, 0, stream>>>(W0, W1, W2, W3, W4, W5, W6, W7, Wc, b7, wsb, wsf);
  nerf_kernel<<<2048, 512, 0, stream>>>(pts, dirs, b0, b1, b2, b3, b4, b5, b6, b7,
                                        Wc, bc, Wo, bo, wsb, wsf, (float*)d_out);
}